// Round 2
// baseline (7651.637 us; speedup 1.0000x reference)
//
#include <hip/hip_runtime.h>
#include <math.h>

// ---- problem constants ----
#define BB 128
#define LL 200
#define DM 320
#define RTOT (BB*LL)          // 25600
#define NCH 129
#define DIN 640               // 2*DM
#define HM 20                 // mamba heads
#define PP 32                 // headdim
#define NN 32                 // d_state
#define CDIM 704              // DIN + 2*NN
#define DPROJ 1364            // 2*DIN + 2*NN + HM
#define NH 16                 // attn heads
#define HD 20                 // DM/NH
#define ATTN_SCALE 0.22360679774997896f  // 1/sqrt(20)

// batch chunking (sequences independent) to keep d_ws footprint small
#define CH 32                 // sequences per chunk
#define NCHUNK 4
#define RC (CH*LL)            // 6400 rows per chunk

static __device__ __forceinline__ float sigmoidf_(float x){ return 1.f/(1.f+__expf(-x)); }
static __device__ __forceinline__ float geluf_(float x){ return 0.5f*x*(1.f+erff(x*0.70710678118654752f)); }

// ---------------- transpose x: (B,129,200) -> (B*200,129)
__global__ __launch_bounds__(256) void k_transpose(const float* __restrict__ x, float* __restrict__ xT){
  int idx = blockIdx.x*256 + threadIdx.x;
  if (idx >= BB*LL*NCH) return;
  int r = idx / NCH, c = idx - r*NCH;
  int b = r / LL, l = r - b*LL;
  xT[idx] = x[((size_t)b*NCH + c)*LL + l];
}

// ---------------- generic fp32 GEMM: C[M,N] = act(A[M,K] @ W[N,K]^T + bias) (+C if accum)
#define BM 128
#define BN 64
#define BKK 16
__global__ __launch_bounds__(256) void k_gemm(const float* __restrict__ A, const float* __restrict__ W,
    const float* __restrict__ bias, float* __restrict__ C, int M, int N, int K, int act, int accum){
  __shared__ float As[BKK][BM+4];
  __shared__ float Ws[BKK][BN+4];
  int tid = threadIdx.x;
  int m0 = blockIdx.y*BM, n0 = blockIdx.x*BN;
  int tx = tid & 15, ty = tid >> 4;
  float acc[8][4];
  #pragma unroll
  for (int i=0;i<8;i++)
    #pragma unroll
    for (int j=0;j<4;j++) acc[i][j]=0.f;
  bool kvec = ((K & 3) == 0);
  for (int k0 = 0; k0 < K; k0 += BKK) {
    if (kvec) {
      int r = tid >> 2, c4 = (tid & 3) << 2;
      #pragma unroll
      for (int hfl = 0; hfl < 2; hfl++) {
        int rr = r + hfl*64;
        float4 v = make_float4(0.f,0.f,0.f,0.f);
        if (m0 + rr < M && k0 + c4 < K)
          v = *(const float4*)(A + (size_t)(m0+rr)*K + k0 + c4);
        As[c4+0][rr]=v.x; As[c4+1][rr]=v.y; As[c4+2][rr]=v.z; As[c4+3][rr]=v.w;
      }
      {
        int n = tid >> 2;
        float4 v = make_float4(0.f,0.f,0.f,0.f);
        if (n0 + n < N && k0 + c4 < K)
          v = *(const float4*)(W + (size_t)(n0+n)*K + k0 + c4);
        Ws[c4+0][n]=v.x; Ws[c4+1][n]=v.y; Ws[c4+2][n]=v.z; Ws[c4+3][n]=v.w;
      }
    } else {
      #pragma unroll
      for (int e = 0; e < 8; e++) {
        int lin = e*256 + tid;
        int r = lin >> 4, c = lin & 15;
        float v = 0.f;
        if (m0 + r < M && k0 + c < K) v = A[(size_t)(m0+r)*K + k0 + c];
        As[c][r] = v;
      }
      #pragma unroll
      for (int e = 0; e < 4; e++) {
        int lin = e*256 + tid;
        int n = lin >> 4, c = lin & 15;
        float v = 0.f;
        if (n0 + n < N && k0 + c < K) v = W[(size_t)(n0+n)*K + k0 + c];
        Ws[c][n] = v;
      }
    }
    __syncthreads();
    #pragma unroll
    for (int kk = 0; kk < BKK; kk++) {
      float af[8], bf[4];
      float4 a0 = *(const float4*)&As[kk][ty*8];
      float4 a1 = *(const float4*)&As[kk][ty*8+4];
      af[0]=a0.x; af[1]=a0.y; af[2]=a0.z; af[3]=a0.w;
      af[4]=a1.x; af[5]=a1.y; af[6]=a1.z; af[7]=a1.w;
      float4 b0 = *(const float4*)&Ws[kk][tx*4];
      bf[0]=b0.x; bf[1]=b0.y; bf[2]=b0.z; bf[3]=b0.w;
      #pragma unroll
      for (int i=0;i<8;i++)
        #pragma unroll
        for (int j=0;j<4;j++) acc[i][j] = fmaf(af[i], bf[j], acc[i][j]);
    }
    __syncthreads();
  }
  #pragma unroll
  for (int i=0;i<8;i++){
    int m = m0 + ty*8 + i;
    if (m >= M) continue;
    #pragma unroll
    for (int j=0;j<4;j++){
      int n = n0 + tx*4 + j;
      if (n >= N) continue;
      float v = acc[i][j];
      if (bias) v += bias[n];
      if (act == 1) v = geluf_(v);
      else if (act == 2) v = tanhf(v);
      size_t off = (size_t)m*N + n;
      if (accum) v += C[off];
      C[off] = v;
    }
  }
}

// ---------------- LayerNorm over 320; out = LN(A (+Badd)) * w + b. One wave per row.
__global__ __launch_bounds__(256) void k_ln(const float* __restrict__ A, const float* __restrict__ Badd,
    float* __restrict__ O, const float* __restrict__ w, const float* __restrict__ b, int nrows){
  int wid = threadIdx.x >> 6, lane = threadIdx.x & 63;
  int row = blockIdx.x*4 + wid;
  if (row >= nrows) return;
  const float* a = A + (size_t)row*DM;
  float x[5]; float s = 0.f;
  #pragma unroll
  for (int j=0;j<5;j++){
    int c = lane + j*64;
    x[j] = a[c];
    if (Badd) x[j] += Badd[(size_t)row*DM + c];
    s += x[j];
  }
  #pragma unroll
  for (int m=1;m<64;m<<=1) s += __shfl_xor(s, m);
  float mean = s * (1.f/DM);
  float vs = 0.f;
  #pragma unroll
  for (int j=0;j<5;j++){ float d = x[j]-mean; vs += d*d; }
  #pragma unroll
  for (int m=1;m<64;m<<=1) vs += __shfl_xor(vs, m);
  float inv = rsqrtf(vs*(1.f/DM) + 1e-5f);
  float* o = O + (size_t)row*DM;
  #pragma unroll
  for (int j=0;j<5;j++){
    int c = lane + j*64;
    o[c] = (x[j]-mean)*inv*w[c] + b[c];
  }
}

// ---------------- attention pass 1: per (b,h) with b chunk-local; online softmax -> o, store (m,l)
__global__ __launch_bounds__(256) void k_attn1(const float* __restrict__ qkv,
    float* __restrict__ oout, float* __restrict__ ml){
  __shared__ float Ks[LL*HD];
  __shared__ float Vs[LL*HD];
  int b = blockIdx.x >> 4, h = blockIdx.x & 15;
  int tid = threadIdx.x;
  for (int idx = tid; idx < LL*HD; idx += 256) {
    int r = idx / HD, c = idx - r*HD;
    const float* base = qkv + (size_t)(b*LL+r)*960 + h*HD + c;
    Ks[idx] = base[320];
    Vs[idx] = base[640];
  }
  __syncthreads();
  int q = tid;
  if (q >= LL) return;
  const float* qp = qkv + (size_t)(b*LL+q)*960 + h*HD;
  float qr[HD];
  #pragma unroll
  for (int d4 = 0; d4 < 5; d4++) {
    float4 v = *(const float4*)(qp + d4*4);
    qr[d4*4]=v.x; qr[d4*4+1]=v.y; qr[d4*4+2]=v.z; qr[d4*4+3]=v.w;
  }
  float m = -1e30f, l = 0.f;
  float o[HD];
  #pragma unroll
  for (int d=0; d<HD; d++) o[d]=0.f;
  for (int k = 0; k < LL; k++) {
    float s = 0.f;
    #pragma unroll
    for (int d = 0; d < HD; d++) s = fmaf(qr[d], Ks[k*HD+d], s);
    s *= ATTN_SCALE;
    float nm = fmaxf(m, s);
    float al = __expf(m - nm);
    float p  = __expf(s - nm);
    l = l*al + p;
    #pragma unroll
    for (int d = 0; d < HD; d++) o[d] = fmaf(p, Vs[k*HD+d], o[d]*al);
    m = nm;
  }
  float inv = 1.f/l;
  float* op = oout + (size_t)(b*LL+q)*DM + h*HD;
  #pragma unroll
  for (int d = 0; d < HD; d++) op[d] = o[d]*inv;
  size_t mlb = ((size_t)(b*NH+h)*LL + q)*2;
  ml[mlb+0] = m;
  ml[mlb+1] = l;
}

// ---------------- attention pass 2: head-mean probabilities, tiled 32q x 32k, chunk-local b
#define QS 164
__global__ __launch_bounds__(256) void k_attnmean(const float* __restrict__ qkv,
    const float* __restrict__ ml, float* __restrict__ outp){
  __shared__ float Qs[32*QS];
  __shared__ float Ksh[32*QS];
  __shared__ float Ms[NH*32];
  __shared__ float Ls[NH*32];
  int b = blockIdx.z;
  int q0 = blockIdx.y*32, k0 = blockIdx.x*32;
  int tid = threadIdx.x;
  for (int idx = tid; idx < NH*32; idx += 256) {
    int h = idx >> 5, r = idx & 31;
    int q = q0 + r;
    float m = 0.f, li = 1.f;
    if (q < LL) {
      size_t base = ((size_t)(b*NH+h)*LL + q)*2;
      m = ml[base+0];
      li = 1.f/ml[base+1];
    }
    Ms[idx] = m; Ls[idx] = li;
  }
  int tx = tid & 31, ty = tid >> 5; // ty 0..7
  float acc[4] = {0.f,0.f,0.f,0.f};
  for (int hc = 0; hc < 2; hc++) {
    __syncthreads();
    for (int idx = tid; idx < 32*160; idx += 256) {
      int r = idx / 160, c = idx - r*160;
      int q = q0 + r, k = k0 + r;
      Qs[r*QS + c]  = (q < LL) ? qkv[(size_t)(b*LL+q)*960 + hc*160 + c] : 0.f;
      Ksh[r*QS + c] = (k < LL) ? qkv[(size_t)(b*LL+k)*960 + 320 + hc*160 + c] : 0.f;
    }
    __syncthreads();
    #pragma unroll
    for (int hh = 0; hh < 8; hh++) {
      int h = hc*8 + hh;
      float kf[HD];
      #pragma unroll
      for (int d4 = 0; d4 < 5; d4++) {
        float4 v = *(const float4*)&Ksh[tx*QS + hh*HD + d4*4];
        kf[d4*4]=v.x; kf[d4*4+1]=v.y; kf[d4*4+2]=v.z; kf[d4*4+3]=v.w;
      }
      #pragma unroll
      for (int j = 0; j < 4; j++) {
        int qr = ty + j*8;
        float s = 0.f;
        #pragma unroll
        for (int d4 = 0; d4 < 5; d4++) {
          float4 v = *(const float4*)&Qs[qr*QS + hh*HD + d4*4];
          s += v.x*kf[d4*4] + v.y*kf[d4*4+1] + v.z*kf[d4*4+2] + v.w*kf[d4*4+3];
        }
        acc[j] += __expf(s*ATTN_SCALE - Ms[h*32 + qr]) * Ls[h*32 + qr];
      }
    }
  }
  #pragma unroll
  for (int j = 0; j < 4; j++) {
    int q = q0 + ty + j*8, k = k0 + tx;
    if (q < LL && k < LL)
      outp[(size_t)(b*LL+q)*LL + k] = acc[j] * (1.f/NH);
  }
}

// ---------------- dt = softplus(zxbcdt[...,-20:]+dt_bias); dA = exp(-exp(A_log)*dt)
__global__ __launch_bounds__(256) void k_dtdA(const float* __restrict__ big, const float* __restrict__ dtb,
    const float* __restrict__ alog, float* __restrict__ dt, float* __restrict__ da, int nrows){
  int idx = blockIdx.x*256 + threadIdx.x;
  if (idx >= nrows*HM) return;
  int row = idx / HM, h = idx - row*HM;
  float raw = big[(size_t)row*DPROJ + 1344 + h] + dtb[h];
  float sp = (raw > 30.f) ? raw : log1pf(__expf(raw));
  dt[idx] = sp;
  da[idx] = __expf(-__expf(alog[h]) * sp);
}

// ---------------- causal depthwise conv (width 4) + silu on xBC (cols 640..1343 of big)
__global__ __launch_bounds__(256) void k_conv(const float* __restrict__ big, const float* __restrict__ cw,
    const float* __restrict__ cb, float* __restrict__ xc, int nrows){
  int idx = blockIdx.x*256 + threadIdx.x;
  if (idx >= nrows*CDIM) return;
  int row = idx / CDIM, c = idx - row*CDIM;
  int l = row % LL;
  float acc = cb[c];
  #pragma unroll
  for (int k = 0; k < 4; k++) {
    int li = l - 3 + k;
    if (li >= 0) acc = fmaf(big[(size_t)(row-3+k)*DPROJ + 640 + c], cw[c*4+k], acc);
  }
  xc[idx] = acc * sigmoidf_(acc);
}

// ---------------- selective scan: per (b,h) with b chunk-local, state 32x32 over 200 steps
__global__ __launch_bounds__(256) void k_scan(const float* __restrict__ xc, const float* __restrict__ dt,
    const float* __restrict__ da, float* __restrict__ y){
  __shared__ float xs[LL*PP];
  __shared__ float dts[LL];
  __shared__ float das[LL];
  int b = blockIdx.x / HM, h = blockIdx.x - (blockIdx.x/HM)*HM;
  int tid = threadIdx.x;
  for (int idx = tid; idx < LL*PP; idx += 256) {
    int r = idx >> 5, c = idx & 31;
    xs[idx] = xc[(size_t)(b*LL+r)*CDIM + h*PP + c];
  }
  for (int idx = tid; idx < LL; idx += 256) {
    dts[idx] = dt[(b*LL+idx)*HM + h];
    das[idx] = da[(b*LL+idx)*HM + h];
  }
  __syncthreads();
  int p = tid >> 3, ng = tid & 7, n0 = ng*4;
  float st0=0.f, st1=0.f, st2=0.f, st3=0.f;
  const float* base = xc + (size_t)(b*LL)*CDIM;
  float4 Bc = *(const float4*)(base + 640 + n0);
  float4 Cc = *(const float4*)(base + 672 + n0);
  for (int t = 0; t < LL; t++) {
    float4 Bn = Bc, Cn = Cc;
    if (t < LL-1) {
      Bn = *(const float4*)(base + (size_t)(t+1)*CDIM + 640 + n0);
      Cn = *(const float4*)(base + (size_t)(t+1)*CDIM + 672 + n0);
    }
    float dav = das[t], dtv = dts[t];
    float coef = dtv * xs[t*PP + p];
    st0 = fmaf(coef, Bc.x, st0*dav);
    st1 = fmaf(coef, Bc.y, st1*dav);
    st2 = fmaf(coef, Bc.z, st2*dav);
    st3 = fmaf(coef, Bc.w, st3*dav);
    float part = st0*Cc.x + st1*Cc.y + st2*Cc.z + st3*Cc.w;
    part += __shfl_xor(part, 1);
    part += __shfl_xor(part, 2);
    part += __shfl_xor(part, 4);
    if (ng == 0) y[(size_t)(b*LL+t)*DIN + h*PP + p] = part;
    Bc = Bn; Cc = Cn;
  }
}

// ---------------- mamba epilogue: y = rmsnorm_640((ys + D*xh)*silu(z)) * gn_w  (in-place on y)
__global__ __launch_bounds__(256) void k_mpost(float* __restrict__ y, const float* __restrict__ xc,
    const float* __restrict__ zbuf, const float* __restrict__ Dp, const float* __restrict__ gw, int nrows){
  int wid = threadIdx.x >> 6, lane = threadIdx.x & 63;
  int row = blockIdx.x*4 + wid;
  if (row >= nrows) return;
  float v[10]; float ss = 0.f;
  #pragma unroll
  for (int j = 0; j < 10; j++) {
    int c = lane + j*64;
    float ys = y[(size_t)row*DIN + c];
    float xh = xc[(size_t)row*CDIM + c];
    float z  = zbuf[(size_t)row*DPROJ + c];
    float val = (ys + Dp[c>>5]*xh) * (z * sigmoidf_(z));
    v[j] = val; ss += val*val;
  }
  #pragma unroll
  for (int m=1;m<64;m<<=1) ss += __shfl_xor(ss, m);
  float scale = rsqrtf(ss*(1.f/DIN) + 1e-5f);
  #pragma unroll
  for (int j = 0; j < 10; j++) {
    int c = lane + j*64;
    y[(size_t)row*DIN + c] = v[j]*scale*gw[c];
  }
}

// ---------------- pool2: logits[row] = dot(A[row,0:80], w2) + b2
__global__ __launch_bounds__(256) void k_pool2(const float* __restrict__ A, const float* __restrict__ w2,
    const float* __restrict__ b2, float* __restrict__ out, int nrows){
  int row = blockIdx.x*256 + threadIdx.x;
  if (row >= nrows) return;
  float s = b2[0];
  const float* a = A + (size_t)row*80;
  #pragma unroll
  for (int j = 0; j < 80; j++) s = fmaf(a[j], w2[j], s);
  out[row] = s;
}

// ---------------- softmax over L + attention-pool. One block per b.
__global__ __launch_bounds__(256) void k_pool(const float* __restrict__ logits, const float* __restrict__ h,
    float* __restrict__ a_out, float* __restrict__ pooled){
  __shared__ float red[256];
  __shared__ float as_[LL];
  int b = blockIdx.x, tid = threadIdx.x;
  float v = (tid < LL) ? logits[b*LL + tid] : -1e30f;
  red[tid] = v; __syncthreads();
  for (int s=128; s>0; s>>=1){ if (tid<s) red[tid]=fmaxf(red[tid],red[tid+s]); __syncthreads(); }
  float mx = red[0]; __syncthreads();
  float e = (tid<LL) ? __expf(v - mx) : 0.f;
  red[tid] = e; __syncthreads();
  for (int s=128; s>0; s>>=1){ if (tid<s) red[tid]+=red[tid+s]; __syncthreads(); }
  float inv = 1.f/red[0];
  if (tid < LL){ float av = e*inv; as_[tid]=av; a_out[b*LL+tid]=av; }
  __syncthreads();
  for (int d = tid; d < DM; d += 256) {
    float s = 0.f;
    for (int l=0;l<LL;l++) s = fmaf(h[(size_t)(b*LL+l)*DM + d], as_[l], s);
    pooled[b*DM + d] = s;
  }
}

// ---------------- head final dot: out[b] = dot(hr[b,0:160], w2) + b2
__global__ __launch_bounds__(128) void k_head2(const float* __restrict__ hr, const float* __restrict__ w2,
    const float* __restrict__ b2, float* __restrict__ out){
  int b = threadIdx.x;
  if (b >= BB) return;
  float s = b2[0];
  const float* a = hr + (size_t)b*160;
  #pragma unroll
  for (int j = 0; j < 160; j++) s = fmaf(a[j], w2[j], s);
  out[b] = s;
}

// ---------------- host side ----------------
static inline void gemm_launch(const float* A, const float* W, const float* bias, float* C,
    int M, int N, int K, int act, int accum, hipStream_t s){
  dim3 g((N+BN-1)/BN, (M+BM-1)/BM);
  hipLaunchKernelGGL(k_gemm, g, dim3(256), 0, s, A, W, bias, C, M, N, K, act, accum);
}

// ---- workspace layout (float offsets), total 33,971,200 floats = 135.9 MB ----
#define F_H    ((size_t)0)           // 8,192,000  (RTOT*320) persistent hidden
#define F_T    ((size_t)8192000)     // 8,192,000  (RTOT*320) LN-out / attn-o / ff2-dest
#define F_S    ((size_t)16384000)    // 17,587,200 general scratch, time-shared:
// mamba chunk layout within S:
#define F_BIGC ((size_t)16384000)    // 8,729,600  (RC*1364)
#define F_XCC  ((size_t)25113600)    // 4,505,600  (RC*704)
#define F_YC   ((size_t)29619200)    // 4,096,000  (RC*640)
#define F_DTC  ((size_t)33715200)    // 128,000    (RC*20)
#define F_DAC  ((size_t)33843200)    // 128,000    -> end 33,971,200
// attention layout within S:
#define F_QKVC ((size_t)16384000)    // 6,144,000  (RC*960)
#define F_MLC  ((size_t)22528000)    // 204,800    (CH*16*200*2)
#define F_DEST ((size_t)22732800)    // 8,192,000  (RTOT*320) -> end 30,924,800
// FF layout within S:
#define F_FF1  ((size_t)16384000)    // 16,384,000 (RTOT*640) -> end 32,768,000
// transpose layout within S:
#define F_XT   ((size_t)16384000)    // 3,302,400  (RTOT*129)
// pooling layout within S:
#define F_P1   ((size_t)16384000)    // 2,048,000  (RTOT*80)
#define F_LOG  ((size_t)18432000)    // 25,600
#define F_PL   ((size_t)18457600)    // 40,960     (BB*320)
#define F_HR   ((size_t)18498560)    // 20,480     (BB*160)

// output layout (floats): (out, sp_attn, post_attn, a)
#define O_OUT ((size_t)0)
#define O_A1  ((size_t)128)
#define O_A2  ((size_t)5120128)
#define O_A   ((size_t)10240128)

extern "C" void kernel_launch(void* const* d_in, const int* in_sizes, int n_in,
                              void* d_out, int out_size, void* d_ws, size_t ws_size,
                              hipStream_t stream) {
  const float* x         = (const float*)d_in[0];
  const float* sp_conv_w = (const float*)d_in[1];
  const float* sp_conv_b = (const float*)d_in[2];
  const float* sp_qkv_w  = (const float*)d_in[3];
  const float* sp_qkv_b  = (const float*)d_in[4];
  const float* sp_out_w  = (const float*)d_in[5];
  const float* sp_out_b  = (const float*)d_in[6];
  const float* sp_ln1_w  = (const float*)d_in[7];
  const float* sp_ln1_b  = (const float*)d_in[8];
  const float* sp_ff1_w  = (const float*)d_in[9];
  const float* sp_ff1_b  = (const float*)d_in[10];
  const float* sp_ff2_w  = (const float*)d_in[11];
  const float* sp_ff2_b  = (const float*)d_in[12];
  const float* sp_ln2_w  = (const float*)d_in[13];
  const float* sp_ln2_b  = (const float*)d_in[14];
  const float* norm_in_w = (const float*)d_in[15];
  const float* norm_in_b = (const float*)d_in[16];
  const float* m_in_w    = (const float*)d_in[17];
  const float* m_conv_w  = (const float*)d_in[18];
  const float* m_conv_b  = (const float*)d_in[19];
  const float* m_dt_bias = (const float*)d_in[20];
  const float* m_A_log   = (const float*)d_in[21];
  const float* m_D       = (const float*)d_in[22];
  const float* m_gnorm_w = (const float*)d_in[23];
  const float* m_out_w   = (const float*)d_in[24];
  const float* ln_w      = (const float*)d_in[25];
  const float* ln_b      = (const float*)d_in[26];
  const float* pm_qkv_w  = (const float*)d_in[27];
  const float* pm_qkv_b  = (const float*)d_in[28];
  const float* pm_out_w  = (const float*)d_in[29];
  const float* pm_out_b  = (const float*)d_in[30];
  const float* pm_ln_w   = (const float*)d_in[31];
  const float* pm_ln_b   = (const float*)d_in[32];
  const float* pool_w1   = (const float*)d_in[33];
  const float* pool_b1   = (const float*)d_in[34];
  const float* pool_w2   = (const float*)d_in[35];
  const float* pool_b2   = (const float*)d_in[36];
  const float* head_w1   = (const float*)d_in[37];
  const float* head_b1   = (const float*)d_in[38];
  const float* head_w2   = (const float*)d_in[39];
  const float* head_b2   = (const float*)d_in[40];

  float* ws  = (float*)d_ws;
  float* H   = ws + F_H;
  float* T   = ws + F_T;
  float* out = (float*)d_out;

  // ---- input projection: h = einsum('bcl,dc->bld') + b ----
  hipLaunchKernelGGL(k_transpose, dim3((BB*LL*NCH+255)/256), dim3(256), 0, stream, x, ws + F_XT);
  gemm_launch(ws + F_XT, sp_conv_w, sp_conv_b, H, RTOT, DM, NCH, 0, 0, stream);

  // ---- spatial MHA (chunked over batch) ----
  for (int c = 0; c < NCHUNK; c++) {
    const float* Hc = H + (size_t)c*RC*DM;
    gemm_launch(Hc, sp_qkv_w, sp_qkv_b, ws + F_QKVC, RC, 3*DM, DM, 0, 0, stream);
    hipLaunchKernelGGL(k_attn1, dim3(CH*NH), dim3(256), 0, stream, ws + F_QKVC,
                       T + (size_t)c*RC*DM, ws + F_MLC);
    hipLaunchKernelGGL(k_attnmean, dim3(7,7,CH), dim3(256), 0, stream, ws + F_QKVC,
                       ws + F_MLC, out + O_A1 + (size_t)c*RC*LL);
  }
  gemm_launch(T, sp_out_w, sp_out_b, ws + F_DEST, RTOT, DM, DM, 0, 0, stream);
  hipLaunchKernelGGL(k_ln, dim3(RTOT/4), dim3(256), 0, stream, H, ws + F_DEST, H, sp_ln1_w, sp_ln1_b, RTOT);

  // ---- FF ----
  gemm_launch(H, sp_ff1_w, sp_ff1_b, ws + F_FF1, RTOT, DIN, DM, 1, 0, stream);
  gemm_launch(ws + F_FF1, sp_ff2_w, sp_ff2_b, T, RTOT, DM, DIN, 0, 0, stream);
  hipLaunchKernelGGL(k_ln, dim3(RTOT/4), dim3(256), 0, stream, H, T, H, sp_ln2_w, sp_ln2_b, RTOT);
  hipLaunchKernelGGL(k_ln, dim3(RTOT/4), dim3(256), 0, stream, H, (const float*)nullptr, H, norm_in_w, norm_in_b, RTOT);

  // ---- mamba layers (each chunked over batch) ----
  for (int i = 0; i < 4; i++) {
    hipLaunchKernelGGL(k_ln, dim3(RTOT/4), dim3(256), 0, stream, H, (const float*)nullptr, T,
                       ln_w + (size_t)i*DM, ln_b + (size_t)i*DM, RTOT);
    for (int c = 0; c < NCHUNK; c++) {
      const float* Tc = T + (size_t)c*RC*DM;
      float* BIGc = ws + F_BIGC;
      float* XCc  = ws + F_XCC;
      float* Yc   = ws + F_YC;
      float* DTc  = ws + F_DTC;
      float* DAc  = ws + F_DAC;
      gemm_launch(Tc, m_in_w + (size_t)i*DPROJ*DM, nullptr, BIGc, RC, DPROJ, DM, 0, 0, stream);
      hipLaunchKernelGGL(k_dtdA, dim3((RC*HM+255)/256), dim3(256), 0, stream, BIGc,
                         m_dt_bias + (size_t)i*HM, m_A_log + (size_t)i*HM, DTc, DAc, RC);
      hipLaunchKernelGGL(k_conv, dim3((RC*CDIM+255)/256), dim3(256), 0, stream, BIGc,
                         m_conv_w + (size_t)i*CDIM*4, m_conv_b + (size_t)i*CDIM, XCc, RC);
      hipLaunchKernelGGL(k_scan, dim3(CH*HM), dim3(256), 0, stream, XCc, DTc, DAc, Yc);
      hipLaunchKernelGGL(k_mpost, dim3(RC/4), dim3(256), 0, stream, Yc, XCc, BIGc,
                         m_D + (size_t)i*HM, m_gnorm_w + (size_t)i*DIN, RC);
      gemm_launch(Yc, m_out_w + (size_t)i*DM*DIN, nullptr, H + (size_t)c*RC*DM, RC, DM, DIN, 0, 1, stream);
    }
  }

  // ---- post MHA (chunked) ----
  for (int c = 0; c < NCHUNK; c++) {
    const float* Hc = H + (size_t)c*RC*DM;
    gemm_launch(Hc, pm_qkv_w, pm_qkv_b, ws + F_QKVC, RC, 3*DM, DM, 0, 0, stream);
    hipLaunchKernelGGL(k_attn1, dim3(CH*NH), dim3(256), 0, stream, ws + F_QKVC,
                       T + (size_t)c*RC*DM, ws + F_MLC);
    hipLaunchKernelGGL(k_attnmean, dim3(7,7,CH), dim3(256), 0, stream, ws + F_QKVC,
                       ws + F_MLC, out + O_A2 + (size_t)c*RC*LL);
  }
  gemm_launch(T, pm_out_w, pm_out_b, ws + F_DEST, RTOT, DM, DM, 0, 0, stream);
  hipLaunchKernelGGL(k_ln, dim3(RTOT/4), dim3(256), 0, stream, H, ws + F_DEST, H, pm_ln_w, pm_ln_b, RTOT);

  // ---- attention pooling + head ----
  gemm_launch(H, pool_w1, pool_b1, ws + F_P1, RTOT, 80, DM, 2, 0, stream);
  hipLaunchKernelGGL(k_pool2, dim3((RTOT+255)/256), dim3(256), 0, stream, ws + F_P1, pool_w2, pool_b2, ws + F_LOG, RTOT);
  hipLaunchKernelGGL(k_pool, dim3(BB), dim3(256), 0, stream, ws + F_LOG, H, out + O_A, ws + F_PL);
  gemm_launch(ws + F_PL, head_w1, head_b1, ws + F_HR, BB, 160, DM, 1, 0, stream);
  hipLaunchKernelGGL(k_head2, dim3(1), dim3(128), 0, stream, ws + F_HR, head_w2, head_b2, out + O_OUT);
}